// Round 4
// baseline (49.782 us; speedup 1.0000x reference)
//
#include <hip/hip_runtime.h>

// out[d][c][h][w] = (h < d) ? left[c][h][w] - right[c][h + 128 - d][w] : 0
// N=1, C=16, H=128, W=256, D=128. Output (1,128,16,128,256) fp32 = 256 MiB.
//
// Bijection: data row (d,c,h) <-> input-row pair (h, hs=h+128-d) with h < hs.
// A wave caching 8 left rows + 8 right rows (1 row = 256 fp32 = one wave-wide
// float4) emits 64 output rows from 16 loads -> 4x read amortization.
// Zero region (h >= d) is written by pure-fill waves; each slice pair
// (d, 127-d) has 129 zero rows, split 65/64 across TWO waves for balance.
// Output stores are non-temporal (evict-first) so the 4 MiB of inputs stay
// L2-resident under the 256 MiB write stream.
//
// Wave plan (4224 waves = 1056 blocks x 4):
//   [0,1920)     full tiles i<j: 64 data rows each (64 KiB stores)
//   [1920,2176)  diagonal tiles i==j: 28 rows each
//   [2176,4224)  zero waves: ~64.5 rows each

typedef float f32x4 __attribute__((ext_vector_type(4)));

__global__ __launch_bounds__(256) void CostDifference_kernel(
    const f32x4* __restrict__ left,
    const f32x4* __restrict__ right,
    f32x4* __restrict__ out)
{
    const int wave = (blockIdx.x << 2) | (threadIdx.x >> 6);
    const int lane = threadIdx.x & 63;

    if (wave < 1920) {
        // ---- full 8x8 row-pair tile, i < j: all 64 pairs valid ----
        const int c = wave & 15;
        int p = wave >> 4;                       // 0..119
        int i = 0;
        while (p >= 15 - i) { p -= 15 - i; ++i; }   // wave-uniform decode
        const int j = i + 1 + p;

        const int i8 = i << 3, j8 = j << 3;
        f32x4 L[8], R[8];
#pragma unroll
        for (int a = 0; a < 8; ++a) L[a] = left [(c * 128 + i8 + a) * 64 + lane];
#pragma unroll
        for (int b = 0; b < 8; ++b) R[b] = right[(c * 128 + j8 + b) * 64 + lane];

        // d = 128 + (i8+a) - (j8+b);  row = d*2048 + c*128 + (i8+a)
        const int base = (128 + i8 - j8) * 2048 + c * 128 + i8;
#pragma unroll
        for (int a = 0; a < 8; ++a) {
#pragma unroll
            for (int b = 0; b < 8; ++b) {
                const int row = base + a * 2049 - b * 2048;
                f32x4 o;
                o.x = L[a].x - R[b].x;
                o.y = L[a].y - R[b].y;
                o.z = L[a].z - R[b].z;
                o.w = L[a].w - R[b].w;
                __builtin_nontemporal_store(o, &out[row * 64 + lane]);
            }
        }
    } else if (wave < 2176) {
        // ---- diagonal tile i == j: pairs a < b (28 rows) ----
        const int t = wave - 1920;
        const int c = t & 15;
        const int i8 = (t >> 4) << 3;
        f32x4 L[8], R[8];
#pragma unroll
        for (int a = 0; a < 8; ++a) L[a] = left [(c * 128 + i8 + a) * 64 + lane];
#pragma unroll
        for (int b = 0; b < 8; ++b) R[b] = right[(c * 128 + i8 + b) * 64 + lane];

        const int base = 128 * 2048 + c * 128 + i8;   // i8 - j8 == 0
#pragma unroll
        for (int a = 0; a < 8; ++a) {
#pragma unroll
            for (int b = 0; b < 8; ++b) {
                if (a < b) {
                    const int row = base + a * 2049 - b * 2048;
                    f32x4 o;
                    o.x = L[a].x - R[b].x;
                    o.y = L[a].y - R[b].y;
                    o.z = L[a].z - R[b].z;
                    o.w = L[a].w - R[b].w;
                    __builtin_nontemporal_store(o, &out[row * 64 + lane]);
                }
            }
        }
    } else {
        // ---- zero waves: slice pair (d, 127-d), 129 rows split 65/64 ----
        const int zw = wave - 2176;              // 0..2047
        const int c    = zw & 15;
        const int t    = zw >> 4;                // 0..127
        const int d    = t >> 1;                 // 0..63
        const int half = t & 1;
        const int d2   = 127 - d;
        const int n1   = 128 - d;                // zero rows in slice d
        const int start = half ? 65 : 0;
        const int end   = half ? 129 : 65;
        const f32x4 zero = {0.f, 0.f, 0.f, 0.f};

        // slice d: rows d+kk for kk in [start, min(end, n1))
        const int e1 = min(end, n1);
        int rb = (d * 2048 + c * 128 + d + start) * 64 + lane;
        for (int kk = start; kk < e1; ++kk, rb += 64) out[rb] = zero;

        // slice d2: rows d2+(kk-n1) for kk in [max(start, n1), end)
        const int s2 = max(start, n1);
        rb = (d2 * 2048 + c * 128 + d2 + (s2 - n1)) * 64 + lane;
        for (int kk = s2; kk < end; ++kk, rb += 64) out[rb] = zero;
    }
}

extern "C" void kernel_launch(void* const* d_in, const int* in_sizes, int n_in,
                              void* d_out, int out_size, void* d_ws, size_t ws_size,
                              hipStream_t stream) {
    const f32x4* left  = (const f32x4*)d_in[0];
    const f32x4* right = (const f32x4*)d_in[1];
    f32x4* out = (f32x4*)d_out;

    CostDifference_kernel<<<1056, 256, 0, stream>>>(left, right, out);
}

// Round 5
// 44.028 us; speedup vs baseline: 1.1307x; 1.1307x over previous
//
#include <hip/hip_runtime.h>

// out[d][c][h][w] = (h < d) ? left[c][h][w] - right[c][h + 128 - d][w] : 0
// N=1, C=16, H=128, W=256, D=128. Output (1,128,16,128,256) fp32 = 256 MiB.
//
// Bijection: data row (d,c,h) <-> input-row pair (h, hs=h+128-d) with h < hs.
// A wave caching 8 left rows + 8 right rows (1 row = 256 fp32 = one wave-wide
// float4) emits 64 output rows from 16 loads -> 4x read amortization.
// Zero region (h >= d): each slice pair (d, 127-d) has 129 zero rows, split
// 65/64 across TWO waves for balance.
// NOTE: nt-stores regressed twice (R2, R4) -> plain stores only.
//
// Wave plan (4224 waves = 1056 blocks x 4):
//   [0,1920)     full tiles i<j: 64 data rows each (64 KiB stores)
//   [1920,2176)  diagonal tiles i==j: 28 rows each
//   [2176,4224)  zero waves: ~64.5 rows each

typedef float f32x4 __attribute__((ext_vector_type(4)));

__global__ __launch_bounds__(256) void CostDifference_kernel(
    const f32x4* __restrict__ left,
    const f32x4* __restrict__ right,
    f32x4* __restrict__ out)
{
    const int wave = (blockIdx.x << 2) | (threadIdx.x >> 6);
    const int lane = threadIdx.x & 63;

    if (wave < 1920) {
        // ---- full 8x8 row-pair tile, i < j: all 64 pairs valid ----
        const int c = wave & 15;
        int p = wave >> 4;                       // 0..119
        int i = 0;
        while (p >= 15 - i) { p -= 15 - i; ++i; }   // wave-uniform decode
        const int j = i + 1 + p;

        const int i8 = i << 3, j8 = j << 3;
        f32x4 L[8], R[8];
#pragma unroll
        for (int a = 0; a < 8; ++a) L[a] = left [(c * 128 + i8 + a) * 64 + lane];
#pragma unroll
        for (int b = 0; b < 8; ++b) R[b] = right[(c * 128 + j8 + b) * 64 + lane];

        // d = 128 + (i8+a) - (j8+b);  row = d*2048 + c*128 + (i8+a)
        const int base = (128 + i8 - j8) * 2048 + c * 128 + i8;
#pragma unroll
        for (int a = 0; a < 8; ++a) {
#pragma unroll
            for (int b = 0; b < 8; ++b) {
                const int row = base + a * 2049 - b * 2048;
                f32x4 o;
                o.x = L[a].x - R[b].x;
                o.y = L[a].y - R[b].y;
                o.z = L[a].z - R[b].z;
                o.w = L[a].w - R[b].w;
                out[row * 64 + lane] = o;
            }
        }
    } else if (wave < 2176) {
        // ---- diagonal tile i == j: pairs a < b (28 rows) ----
        const int t = wave - 1920;
        const int c = t & 15;
        const int i8 = (t >> 4) << 3;
        f32x4 L[8], R[8];
#pragma unroll
        for (int a = 0; a < 8; ++a) L[a] = left [(c * 128 + i8 + a) * 64 + lane];
#pragma unroll
        for (int b = 0; b < 8; ++b) R[b] = right[(c * 128 + i8 + b) * 64 + lane];

        const int base = 128 * 2048 + c * 128 + i8;   // i8 - j8 == 0
#pragma unroll
        for (int a = 0; a < 8; ++a) {
#pragma unroll
            for (int b = 0; b < 8; ++b) {
                if (a < b) {
                    const int row = base + a * 2049 - b * 2048;
                    f32x4 o;
                    o.x = L[a].x - R[b].x;
                    o.y = L[a].y - R[b].y;
                    o.z = L[a].z - R[b].z;
                    o.w = L[a].w - R[b].w;
                    out[row * 64 + lane] = o;
                }
            }
        }
    } else {
        // ---- zero waves: slice pair (d, 127-d), 129 rows split 65/64 ----
        const int zw = wave - 2176;              // 0..2047
        const int c    = zw & 15;
        const int t    = zw >> 4;                // 0..127
        const int d    = t >> 1;                 // 0..63
        const int half = t & 1;
        const int d2   = 127 - d;
        const int n1   = 128 - d;                // zero rows in slice d
        const int start = half ? 65 : 0;
        const int end   = half ? 129 : 65;
        const f32x4 zero = {0.f, 0.f, 0.f, 0.f};

        // slice d: rows d+kk for kk in [start, min(end, n1))
        const int e1 = min(end, n1);
        int rb = (d * 2048 + c * 128 + d + start) * 64 + lane;
        for (int kk = start; kk < e1; ++kk, rb += 64) out[rb] = zero;

        // slice d2: rows d2+(kk-n1) for kk in [max(start, n1), end)
        const int s2 = max(start, n1);
        rb = (d2 * 2048 + c * 128 + d2 + (s2 - n1)) * 64 + lane;
        for (int kk = s2; kk < end; ++kk, rb += 64) out[rb] = zero;
    }
}

extern "C" void kernel_launch(void* const* d_in, const int* in_sizes, int n_in,
                              void* d_out, int out_size, void* d_ws, size_t ws_size,
                              hipStream_t stream) {
    const f32x4* left  = (const f32x4*)d_in[0];
    const f32x4* right = (const f32x4*)d_in[1];
    f32x4* out = (f32x4*)d_out;

    CostDifference_kernel<<<1056, 256, 0, stream>>>(left, right, out);
}